// Round 5
// baseline (223.459 us; speedup 1.0000x reference)
//
#include <hip/hip_runtime.h>
#include <math.h>

// Problem constants
constexpr int B_  = 2;
constexpr int C_  = 256;
constexpr int CQ_ = 64;
constexpr int N_  = 4096;  // 64*64

typedef __attribute__((ext_vector_type(8))) short     short8;  // 8 bf16
typedef __attribute__((ext_vector_type(8))) _Float16  half8;   // 8 f16
typedef __attribute__((ext_vector_type(4))) float     f32x4;   // MFMA C/D

constexpr float SHIFT = 24.0f;   // static softmax shift (exact: shift-invariance)

static __device__ __forceinline__ unsigned short f2bf(float x) {
    union { float f; unsigned u; } v; v.f = x;
    unsigned r = (v.u + 0x7FFFu + ((v.u >> 16) & 1u)) >> 16;  // RNE
    return (unsigned short)r;
}

// ---------------------------------------------------------------------------
// Weight convert: fp32 -> f16, concat [q1|k1|v1|q2|k2|v2] (96K elems/stream)
// ---------------------------------------------------------------------------
__global__ __launch_bounds__(256)
void wconv_kernel(const float* __restrict__ q1w, const float* __restrict__ k1w,
                  const float* __restrict__ v1w, const float* __restrict__ q2w,
                  const float* __restrict__ k2w, const float* __restrict__ v2w,
                  _Float16* __restrict__ wb)
{
    int i = (blockIdx.x * 256 + threadIdx.x) * 4;   // grid 192 -> 196608 elems
    const float* src;
    int off;
    if      (i < 16384)  { src = q1w; off = 0; }
    else if (i < 32768)  { src = k1w; off = 16384; }
    else if (i < 98304)  { src = v1w; off = 32768; }
    else if (i < 114688) { src = q2w; off = 98304; }
    else if (i < 131072) { src = k2w; off = 114688; }
    else                 { src = v2w; off = 131072; }
    float4 f = *(const float4*)(src + (i - off));
    _Float16 h0 = (_Float16)f.x, h1 = (_Float16)f.y;
    _Float16 h2 = (_Float16)f.z, h3 = (_Float16)f.w;
    ushort4 u;
    u.x = *(unsigned short*)&h0; u.y = *(unsigned short*)&h1;
    u.z = *(unsigned short*)&h2; u.w = *(unsigned short*)&h3;
    *(ushort4*)((unsigned short*)wb + i) = u;
}

// ---------------------------------------------------------------------------
// Fused QKV projection (MFMA, f16 inputs, fp32 accum).  (round-0 structure)
// ---------------------------------------------------------------------------
__global__ __launch_bounds__(512)
void proj_kernel(const float* __restrict__ in1, const float* __restrict__ in2,
                 const _Float16* __restrict__ wb,
                 const float* __restrict__ q1b, const float* __restrict__ k1b,
                 const float* __restrict__ v1b, const float* __restrict__ q2b,
                 const float* __restrict__ k2b, const float* __restrict__ v2b,
                 _Float16* __restrict__ q_ws, _Float16* __restrict__ k_ws,
                 unsigned short* __restrict__ v_ws)
{
    __shared__ _Float16 Xs[64 * 264];
    const int bs = blockIdx.y, s = bs >> 1, bb = bs & 1;
    const int n0 = blockIdx.x * 64;
    const float* x = (s ? in2 : in1) + (size_t)bb * C_ * N_;
    const int tid = threadIdx.x;
    const int lane = tid & 63, wave = tid >> 6, quad = lane >> 4, l15 = lane & 15;

    #pragma unroll
    for (int rep = 0; rep < 8; ++rep) {
        int idx = rep * 512 + tid;
        int c = idx >> 4, ng = idx & 15;
        float4 f = *(const float4*)(x + (size_t)c * N_ + n0 + ng * 4);
        Xs[(ng * 4 + 0) * 264 + c] = (_Float16)f.x;
        Xs[(ng * 4 + 1) * 264 + c] = (_Float16)f.y;
        Xs[(ng * 4 + 2) * 264 + c] = (_Float16)f.z;
        Xs[(ng * 4 + 3) * 264 + c] = (_Float16)f.w;
    }
    __syncthreads();

    const _Float16* wqs = wb + (size_t)s * 98304;
    const _Float16* wks = wqs + 16384;
    const _Float16* wvs = wks + 16384;

    // ---- Q/K: waves 0-3 -> Q, 4-7 -> K; n-block = wave&3 ----
    {
        const int m = wave >> 2, nb = wave & 3;
        const _Float16* W = m ? wks : wqs;
        const float* bias = m ? (s ? k2b : k1b) : (s ? q2b : q1b);
        _Float16* outp = (m ? k_ws : q_ws) + (size_t)bs * N_ * CQ_;
        half8 af[8];
        #pragma unroll
        for (int kh = 0; kh < 8; ++kh)
            af[kh] = *(const half8*)(&Xs[(16 * nb + l15) * 264 + quad * 8 + kh * 32]);
        f32x4 a4[4];
        #pragma unroll
        for (int o = 0; o < 4; ++o) a4[o] = (f32x4){0.f, 0.f, 0.f, 0.f};
        #pragma unroll
        for (int kh = 0; kh < 8; ++kh)
            #pragma unroll
            for (int o = 0; o < 4; ++o) {
                half8 bf = *(const half8*)(W + (size_t)(16 * o + l15) * C_ + quad * 8 + kh * 32);
                a4[o] = __builtin_amdgcn_mfma_f32_16x16x32_f16(af[kh], bf, a4[o], 0, 0, 0);
            }
        #pragma unroll
        for (int o = 0; o < 4; ++o) {
            float bv = bias[16 * o + l15];
            #pragma unroll
            for (int r = 0; r < 4; ++r) {
                int n = n0 + 16 * nb + quad * 4 + r;
                outp[(size_t)n * CQ_ + 16 * o + l15] = (_Float16)(a4[o][r] + bv);
            }
        }
    }

    // ---- V: wave owns o-block 32*wave .. +31 ----
    {
        const float* vb = s ? v2b : v1b;
        unsigned short* outp = v_ws + (size_t)bs * C_ * N_;
        f32x4 v4[2][4];
        #pragma unroll
        for (int o = 0; o < 2; ++o)
            #pragma unroll
            for (int nt = 0; nt < 4; ++nt) v4[o][nt] = (f32x4){0.f, 0.f, 0.f, 0.f};
        #pragma unroll
        for (int kh = 0; kh < 8; ++kh) {
            half8 bf[4], af[2];
            #pragma unroll
            for (int nt = 0; nt < 4; ++nt)
                bf[nt] = *(const half8*)(&Xs[(16 * nt + l15) * 264 + quad * 8 + kh * 32]);
            #pragma unroll
            for (int o = 0; o < 2; ++o)
                af[o] = *(const half8*)(wvs + (size_t)(32 * wave + 16 * o + l15) * C_ + quad * 8 + kh * 32);
            #pragma unroll
            for (int o = 0; o < 2; ++o)
                #pragma unroll
                for (int nt = 0; nt < 4; ++nt)
                    v4[o][nt] = __builtin_amdgcn_mfma_f32_16x16x32_f16(af[o], bf[nt], v4[o][nt], 0, 0, 0);
        }
        #pragma unroll
        for (int o = 0; o < 2; ++o)
            #pragma unroll
            for (int r = 0; r < 4; ++r) {
                int c = 32 * wave + 16 * o + quad * 4 + r;
                float bv = vb[c];
                #pragma unroll
                for (int nt = 0; nt < 4; ++nt)
                    outp[(size_t)c * N_ + n0 + 16 * nt + l15] = f2bf(v4[o][nt][r] + bv);
            }
    }
}

// ---------------------------------------------------------------------------
// MFMA flash attention, v6: 16 waves / 1024 threads, asymmetric roles.
// v2-v5 post-mortem: all schedule variants flat at 102us.  Unit accounting:
// per CU-iter MFMA ~194cyc/SIMD (throughput), VALU ~600-700/SIMD (exp+pack,
// only 2 waves/SIMD), LDS ~570/CU, TCP ~770/CU -- each unit at 15-20%, sum ==
// measured time.  2 barrier-locked waves/SIMD cannot overlap units.  Round 1
// showed per-CU-iter fixed costs dominate, so more BLOCKS scales costs; v6
// adds WAVES with identical per-CU unit totals:
//   - waves 0-7: S-role exactly as before (jsub=w&3, ihalf=w>>2): K loads,
//     S MFMA, exp, P-write, l-acc -- totals unchanged.
//   - all 16 waves: PV split (jh=w>>3, wc=w&7): each does the K=32 j-chunk
//     jh for c-block wc.  P-LDS reads/CU unchanged (16x4KB); V TCP unchanged
//     (w, w+8 read disjoint j-halves of same c-rows).
//   - each SIMD hosts 2 S-waves + 2 PV-only waves -> role diversity + 2x
//     latency hiding.  Partial O (jh pairs) reduced once at end via LDS.
// Single-buffered vf/kf (load-after-use); latency spans the barrier.
// ---------------------------------------------------------------------------
__global__ __launch_bounds__(1024)
void flash_kernel(const _Float16* __restrict__ qg,        // [bs][n][64] f16
                  const _Float16* __restrict__ kg,        // [bs][n][64] f16
                  const unsigned short* __restrict__ vg,  // [bs][c][n] bf16
                  const float* __restrict__ in1, const float* __restrict__ in2,
                  const float* __restrict__ gamma_p, float* __restrict__ out)
{
    __shared__ unsigned short Pt[2][64 * 64];   // swizzled, 128 B/row; reused as f32 scratch at end
    __shared__ float lsum[64 * 4];

    const int tid  = threadIdx.x;
    const int lane = tid & 63;
    const int wave = tid >> 6;              // 0..15
    const int quad = lane >> 4;
    const int l15  = lane & 15;
    const int bs   = blockIdx.x & 3;        // one bs per XCD-pair (L2 locality)
    const int q0   = (blockIdx.x >> 2) * 64;
    const int s = bs >> 1, bb = bs & 1;
    // S-role (waves 0-7 only)
    const int jsub  = wave & 3;
    const int ihalf = (wave >> 2) & 1;
    // PV-role (all 16 waves)
    const int wc = wave & 7;                // c-block 32*wc
    const int jh = wave >> 3;               // j-chunk 32*jh of the 64-j tile

    const _Float16* qp = qg + (size_t)bs * N_ * CQ_;
    const _Float16* kp = kg + (size_t)bs * N_ * CQ_;
    const unsigned short* vp = vg + (size_t)bs * C_ * N_;

    unsigned char* ptb0 = (unsigned char*)&Pt[0][0];
    unsigned char* ptb1 = (unsigned char*)&Pt[1][0];

    // loop-invariant lane bases
    const _Float16* kRow = kp + (size_t)(16 * jsub + l15) * CQ_ + quad * 8;      // + t*4096
    const unsigned short* vRow0 = vp + (size_t)(32 * wc + l15) * N_ + 32 * jh + quad * 8;       // + t*64
    const unsigned short* vRow1 = vp + (size_t)(32 * wc + 16 + l15) * N_ + 32 * jh + quad * 8;  // + t*64

    // persistent Q B-frags (S-waves only): i = 32*ihalf + 16*isub + l15
    half8 qf[2][2];
    float lacc[2] = {0.f, 0.f};
    half8 kf[2];            // K(t+1) at top of body t
    short8 vf[2];           // V(t) j-chunk jh at top of body t  [csub]
    f32x4 acc[4][2];        // partial O^T: [is2: i=16is2+quad*4+r][csub: c=32wc+16csub+l15]
    #pragma unroll
    for (int a = 0; a < 4; ++a)
        #pragma unroll
        for (int b = 0; b < 2; ++b) acc[a][b] = (f32x4){0.f, 0.f, 0.f, 0.f};

    // ---------------- prologue ----------------
    if (wave < 8) {
        #pragma unroll
        for (int isub = 0; isub < 2; ++isub)
            #pragma unroll
            for (int kh = 0; kh < 2; ++kh)
                qf[isub][kh] = *(const half8*)(
                    qp + (size_t)(q0 + 32 * ihalf + 16 * isub + l15) * CQ_ + quad * 8 + kh * 32);
        kf[0] = *(const half8*)(kRow);
        kf[1] = *(const half8*)(kRow + 32);
        // S(0) -> Pt[0]
        f32x4 sacc[2];
        sacc[0] = (f32x4){0.f, 0.f, 0.f, 0.f};
        sacc[1] = (f32x4){0.f, 0.f, 0.f, 0.f};
        #pragma unroll
        for (int kh = 0; kh < 2; ++kh)
            #pragma unroll
            for (int isub = 0; isub < 2; ++isub)
                sacc[isub] = __builtin_amdgcn_mfma_f32_16x16x32_f16(
                    kf[kh], qf[isub][kh], sacc[isub], 0, 0, 0);
        #pragma unroll
        for (int isub = 0; isub < 2; ++isub) {
            f32x4 p;
            p.x = __expf(sacc[isub].x - SHIFT);
            p.y = __expf(sacc[isub].y - SHIFT);
            p.z = __expf(sacc[isub].z - SHIFT);
            p.w = __expf(sacc[isub].w - SHIFT);
            lacc[isub] += p.x + p.y + p.z + p.w;
            ushort4 pbv;
            pbv.x = f2bf(p.x); pbv.y = f2bf(p.y); pbv.z = f2bf(p.z); pbv.w = f2bf(p.w);
            int row = 32 * ihalf + 16 * isub + l15;
            int cb  = (32 * jsub + 8 * quad) ^ ((row & 7) << 4);
            *(ushort4*)(ptb0 + row * 128 + cb) = pbv;
        }
        // K(1) for body t=0
        kf[0] = *(const half8*)(kRow + 4096);
        kf[1] = *(const half8*)(kRow + 4096 + 32);
    }
    // V(0) (all waves)
    vf[0] = *(const short8*)(vRow0);
    vf[1] = *(const short8*)(vRow1);

    // ---------------- main loop ----------------
    for (int t = 0; t < 64; ++t) {
        unsigned char* ptr = (t & 1) ? ptb1 : ptb0;        // P(t)
        unsigned char* ptw = (t & 1) ? ptb0 : ptb1;        // P(t+1)

        asm volatile("s_waitcnt lgkmcnt(0)" ::: "memory");
        __builtin_amdgcn_sched_barrier(0);
        __builtin_amdgcn_s_barrier();
        __builtin_amdgcn_sched_barrier(0);

        // ---- PV(t): all waves.  O^T_partial += P[i][32jh..+31] x V ----
        short8 ap[4];
        #pragma unroll
        for (int is2 = 0; is2 < 4; ++is2) {
            int row = 16 * is2 + l15;
            int cb  = (jh * 64 + quad * 16) ^ ((row & 7) << 4);
            ap[is2] = *(const short8*)(ptr + row * 128 + cb);
        }
        __builtin_amdgcn_s_setprio(1);
        #pragma unroll
        for (int is2 = 0; is2 < 4; ++is2)
            #pragma unroll
            for (int csub = 0; csub < 2; ++csub)
                acc[is2][csub] = __builtin_amdgcn_mfma_f32_16x16x32_bf16(
                    ap[is2], vf[csub], acc[is2][csub], 0, 0, 0);
        __builtin_amdgcn_s_setprio(0);

        if (t < 63) {
            // ---- S(t+1) + exp + P-write (S-waves) ----
            if (wave < 8) {
                f32x4 sacc[2];
                sacc[0] = (f32x4){0.f, 0.f, 0.f, 0.f};
                sacc[1] = (f32x4){0.f, 0.f, 0.f, 0.f};
                #pragma unroll
                for (int kh = 0; kh < 2; ++kh)
                    #pragma unroll
                    for (int isub = 0; isub < 2; ++isub)
                        sacc[isub] = __builtin_amdgcn_mfma_f32_16x16x32_f16(
                            kf[kh], qf[isub][kh], sacc[isub], 0, 0, 0);
                #pragma unroll
                for (int isub = 0; isub < 2; ++isub) {
                    f32x4 p;
                    p.x = __expf(sacc[isub].x - SHIFT);
                    p.y = __expf(sacc[isub].y - SHIFT);
                    p.z = __expf(sacc[isub].z - SHIFT);
                    p.w = __expf(sacc[isub].w - SHIFT);
                    lacc[isub] += p.x + p.y + p.z + p.w;
                    ushort4 pbv;
                    pbv.x = f2bf(p.x); pbv.y = f2bf(p.y); pbv.z = f2bf(p.z); pbv.w = f2bf(p.w);
                    int row = 32 * ihalf + 16 * isub + l15;
                    int cb  = (32 * jsub + 8 * quad) ^ ((row & 7) << 4);
                    *(ushort4*)(ptw + row * 128 + cb) = pbv;
                }
                // K(t+2) for next body
                int tk = (t + 2) & 63;
                kf[0] = *(const half8*)(kRow + (size_t)tk * 4096);
                kf[1] = *(const half8*)(kRow + (size_t)tk * 4096 + 32);
            }
            // V(t+1) (all waves; issued after PV consumed vf)
            vf[0] = *(const short8*)(vRow0 + (t + 1) * 64);
            vf[1] = *(const short8*)(vRow1 + (t + 1) * 64);
        }
    }

    // ---- l reduction (S-waves): quad-shfl then cross-jsub via LDS ----
    if (wave < 8) {
        #pragma unroll
        for (int isub = 0; isub < 2; ++isub) {
            float t = lacc[isub];
            t += __shfl_xor(t, 16);
            t += __shfl_xor(t, 32);
            if (quad == 0)
                lsum[(32 * ihalf + 16 * isub + l15) * 4 + jsub] = t;
        }
    }
    __syncthreads();

    // ---- jh-reduction: waves 8-15 hand their partial O to partner wave-8 ----
    float* red = (float*)&Pt[0][0];   // 16 KB scratch (Pt no longer needed)
    #pragma unroll
    for (int r = 0; r < 4; ++r) {
        if (wave >= 8) {
            *(f32x4*)(red + (size_t)(wave - 8) * 512 + lane * 8 + 0) = acc[r][0];
            *(f32x4*)(red + (size_t)(wave - 8) * 512 + lane * 8 + 4) = acc[r][1];
        }
        __syncthreads();
        if (wave < 8) {
            f32x4 a0 = *(const f32x4*)(red + (size_t)wave * 512 + lane * 8 + 0);
            f32x4 a1 = *(const f32x4*)(red + (size_t)wave * 512 + lane * 8 + 4);
            acc[r][0] += a0;
            acc[r][1] += a1;
        }
        __syncthreads();
    }

    // ---- epilogue: normalize + gamma + residual (waves 0-7; wc = wave) ----
    if (wave < 8) {
        const float gamma = gamma_p[0];
        const float* inp = (s ? in2 : in1) + (size_t)bb * C_ * N_;
        float* op = out + (size_t)bs * C_ * N_;
        #pragma unroll
        for (int is2 = 0; is2 < 4; ++is2) {
            float inv[4];
            #pragma unroll
            for (int r = 0; r < 4; ++r) {
                f32x4 t = *(const f32x4*)(&lsum[(16 * is2 + quad * 4 + r) * 4]);
                inv[r] = 1.0f / (t.x + t.y + t.z + t.w);
            }
            #pragma unroll
            for (int csub = 0; csub < 2; ++csub) {
                int c = 32 * wc + 16 * csub + l15;
                #pragma unroll
                for (int r = 0; r < 4; ++r) {
                    int i = q0 + 16 * is2 + quad * 4 + r;
                    size_t idx = (size_t)c * N_ + i;
                    op[idx] = gamma * acc[is2][csub][r] * inv[r] + inp[idx];
                }
            }
        }
    }
}

// ---------------------------------------------------------------------------
extern "C" void kernel_launch(void* const* d_in, const int* in_sizes, int n_in,
                              void* d_out, int out_size, void* d_ws, size_t ws_size,
                              hipStream_t stream)
{
    const float* in1 = (const float*)d_in[0];
    const float* in2 = (const float*)d_in[1];
    const float* q1w = (const float*)d_in[2];
    const float* q1b = (const float*)d_in[3];
    const float* k1w = (const float*)d_in[4];
    const float* k1b = (const float*)d_in[5];
    const float* v1w = (const float*)d_in[6];
    const float* v1b = (const float*)d_in[7];
    const float* q2w = (const float*)d_in[8];
    const float* q2b = (const float*)d_in[9];
    const float* k2w = (const float*)d_in[10];
    const float* k2b = (const float*)d_in[11];
    const float* v2w = (const float*)d_in[12];
    const float* v2b = (const float*)d_in[13];
    const float* gamma = (const float*)d_in[22];
    float* out = (float*)d_out;

    // ws: wb f16 196608 | q[4][4096][64] f16 | k same | v[4][256][4096] bf16
    _Float16* wb   = (_Float16*)d_ws;
    _Float16* q_ws = wb + 196608;
    _Float16* k_ws = q_ws + (size_t)4 * N_ * CQ_;
    unsigned short* v_ws = (unsigned short*)(k_ws + (size_t)4 * N_ * CQ_);

    wconv_kernel<<<dim3(192), 256, 0, stream>>>(q1w, k1w, v1w, q2w, k2w, v2w, wb);
    proj_kernel<<<dim3(64, 4), 512, 0, stream>>>(
        in1, in2, wb, q1b, k1b, v1b, q2b, k2b, v2b, q_ws, k_ws, v_ws);
    flash_kernel<<<dim3(256), 1024, 0, stream>>>(q_ws, k_ws, v_ws, in1, in2, gamma, out);
}

// Round 6
// 186.542 us; speedup vs baseline: 1.1979x; 1.1979x over previous
//
#include <hip/hip_runtime.h>
#include <math.h>

// Problem constants
constexpr int B_  = 2;
constexpr int C_  = 256;
constexpr int CQ_ = 64;
constexpr int N_  = 4096;  // 64*64

typedef __attribute__((ext_vector_type(8))) short     short8;  // 8 bf16
typedef __attribute__((ext_vector_type(8))) _Float16  half8;   // 8 f16
typedef __attribute__((ext_vector_type(4))) float     f32x4;   // MFMA C/D

constexpr float SHIFT = 24.0f;   // static softmax shift (exact: shift-invariance)

static __device__ __forceinline__ unsigned short f2bf(float x) {
    union { float f; unsigned u; } v; v.f = x;
    unsigned r = (v.u + 0x7FFFu + ((v.u >> 16) & 1u)) >> 16;  // RNE
    return (unsigned short)r;
}

// ---------------------------------------------------------------------------
// Weight convert: fp32 -> f16, concat [q1|k1|v1|q2|k2|v2] (96K elems/stream)
// ---------------------------------------------------------------------------
__global__ __launch_bounds__(256)
void wconv_kernel(const float* __restrict__ q1w, const float* __restrict__ k1w,
                  const float* __restrict__ v1w, const float* __restrict__ q2w,
                  const float* __restrict__ k2w, const float* __restrict__ v2w,
                  _Float16* __restrict__ wb)
{
    int i = (blockIdx.x * 256 + threadIdx.x) * 4;   // grid 192 -> 196608 elems
    const float* src;
    int off;
    if      (i < 16384)  { src = q1w; off = 0; }
    else if (i < 32768)  { src = k1w; off = 16384; }
    else if (i < 98304)  { src = v1w; off = 32768; }
    else if (i < 114688) { src = q2w; off = 98304; }
    else if (i < 131072) { src = k2w; off = 114688; }
    else                 { src = v2w; off = 131072; }
    float4 f = *(const float4*)(src + (i - off));
    _Float16 h0 = (_Float16)f.x, h1 = (_Float16)f.y;
    _Float16 h2 = (_Float16)f.z, h3 = (_Float16)f.w;
    ushort4 u;
    u.x = *(unsigned short*)&h0; u.y = *(unsigned short*)&h1;
    u.z = *(unsigned short*)&h2; u.w = *(unsigned short*)&h3;
    *(ushort4*)((unsigned short*)wb + i) = u;
}

// ---------------------------------------------------------------------------
// Fused QKV projection (MFMA, f16 inputs, fp32 accum).  (round-0 structure)
// ---------------------------------------------------------------------------
__global__ __launch_bounds__(512)
void proj_kernel(const float* __restrict__ in1, const float* __restrict__ in2,
                 const _Float16* __restrict__ wb,
                 const float* __restrict__ q1b, const float* __restrict__ k1b,
                 const float* __restrict__ v1b, const float* __restrict__ q2b,
                 const float* __restrict__ k2b, const float* __restrict__ v2b,
                 _Float16* __restrict__ q_ws, _Float16* __restrict__ k_ws,
                 unsigned short* __restrict__ v_ws)
{
    __shared__ _Float16 Xs[64 * 264];
    const int bs = blockIdx.y, s = bs >> 1, bb = bs & 1;
    const int n0 = blockIdx.x * 64;
    const float* x = (s ? in2 : in1) + (size_t)bb * C_ * N_;
    const int tid = threadIdx.x;
    const int lane = tid & 63, wave = tid >> 6, quad = lane >> 4, l15 = lane & 15;

    #pragma unroll
    for (int rep = 0; rep < 8; ++rep) {
        int idx = rep * 512 + tid;
        int c = idx >> 4, ng = idx & 15;
        float4 f = *(const float4*)(x + (size_t)c * N_ + n0 + ng * 4);
        Xs[(ng * 4 + 0) * 264 + c] = (_Float16)f.x;
        Xs[(ng * 4 + 1) * 264 + c] = (_Float16)f.y;
        Xs[(ng * 4 + 2) * 264 + c] = (_Float16)f.z;
        Xs[(ng * 4 + 3) * 264 + c] = (_Float16)f.w;
    }
    __syncthreads();

    const _Float16* wqs = wb + (size_t)s * 98304;
    const _Float16* wks = wqs + 16384;
    const _Float16* wvs = wks + 16384;

    // ---- Q/K: waves 0-3 -> Q, 4-7 -> K; n-block = wave&3 ----
    {
        const int m = wave >> 2, nb = wave & 3;
        const _Float16* W = m ? wks : wqs;
        const float* bias = m ? (s ? k2b : k1b) : (s ? q2b : q1b);
        _Float16* outp = (m ? k_ws : q_ws) + (size_t)bs * N_ * CQ_;
        half8 af[8];
        #pragma unroll
        for (int kh = 0; kh < 8; ++kh)
            af[kh] = *(const half8*)(&Xs[(16 * nb + l15) * 264 + quad * 8 + kh * 32]);
        f32x4 a4[4];
        #pragma unroll
        for (int o = 0; o < 4; ++o) a4[o] = (f32x4){0.f, 0.f, 0.f, 0.f};
        #pragma unroll
        for (int kh = 0; kh < 8; ++kh)
            #pragma unroll
            for (int o = 0; o < 4; ++o) {
                half8 bf = *(const half8*)(W + (size_t)(16 * o + l15) * C_ + quad * 8 + kh * 32);
                a4[o] = __builtin_amdgcn_mfma_f32_16x16x32_f16(af[kh], bf, a4[o], 0, 0, 0);
            }
        #pragma unroll
        for (int o = 0; o < 4; ++o) {
            float bv = bias[16 * o + l15];
            #pragma unroll
            for (int r = 0; r < 4; ++r) {
                int n = n0 + 16 * nb + quad * 4 + r;
                outp[(size_t)n * CQ_ + 16 * o + l15] = (_Float16)(a4[o][r] + bv);
            }
        }
    }

    // ---- V: wave owns o-block 32*wave .. +31 ----
    {
        const float* vb = s ? v2b : v1b;
        unsigned short* outp = v_ws + (size_t)bs * C_ * N_;
        f32x4 v4[2][4];
        #pragma unroll
        for (int o = 0; o < 2; ++o)
            #pragma unroll
            for (int nt = 0; nt < 4; ++nt) v4[o][nt] = (f32x4){0.f, 0.f, 0.f, 0.f};
        #pragma unroll
        for (int kh = 0; kh < 8; ++kh) {
            half8 bf[4], af[2];
            #pragma unroll
            for (int nt = 0; nt < 4; ++nt)
                bf[nt] = *(const half8*)(&Xs[(16 * nt + l15) * 264 + quad * 8 + kh * 32]);
            #pragma unroll
            for (int o = 0; o < 2; ++o)
                af[o] = *(const half8*)(wvs + (size_t)(32 * wave + 16 * o + l15) * C_ + quad * 8 + kh * 32);
            #pragma unroll
            for (int o = 0; o < 2; ++o)
                #pragma unroll
                for (int nt = 0; nt < 4; ++nt)
                    v4[o][nt] = __builtin_amdgcn_mfma_f32_16x16x32_f16(af[o], bf[nt], v4[o][nt], 0, 0, 0);
        }
        #pragma unroll
        for (int o = 0; o < 2; ++o)
            #pragma unroll
            for (int r = 0; r < 4; ++r) {
                int c = 32 * wave + 16 * o + quad * 4 + r;
                float bv = vb[c];
                #pragma unroll
                for (int nt = 0; nt < 4; ++nt)
                    outp[(size_t)c * N_ + n0 + 16 * nt + l15] = f2bf(v4[o][nt][r] + bv);
            }
    }
}

// ---------------------------------------------------------------------------
// Repack K/V into MFMA-fragment-linear layout (v7).
// Theory: flash's K/V wave-loads each touch 16 NON-CONTIGUOUS 64B lines
// (16 rows of [c][n] / [n][64]); the TA/TCP address path processes scattered
// lines far slower than contiguous bursts -> ~3000 cyc/iter/CU, the invariant
// wall all six schedule variants hit.  Fragment-linear layout makes each
// flash load one contiguous 1KB burst:
//   Vf[j32 128][ct 16][lane 64][8]   (bf16)   per bs (1M elems)
//   Kf[jt 256][kh 2][lane 64][8]     (f16)    per bs (256K elems)
// Coalesced read rows -> LDS transpose -> coalesced frag-block write.
// ---------------------------------------------------------------------------
__global__ __launch_bounds__(256)
void repack_kernel(const unsigned short* __restrict__ v_ws,
                   const unsigned short* __restrict__ k_ws,
                   unsigned short* __restrict__ vfo,
                   unsigned short* __restrict__ kfo)
{
    __shared__ unsigned short T[4736];
    const int b = blockIdx.x, t = threadIdx.x;
    if (b < 1024) {
        // V: [c][n] -> frag blocks.  Block handles 16 c x 256 j.
        const int bs = b >> 8, ct = (b >> 4) & 15, j0 = (b & 15) * 256;
        const unsigned short* src = v_ws + (size_t)bs * (C_ * N_) + (size_t)(ct * 16) * N_ + j0;
        {
            const int rr = t >> 4, cc = (t & 15) * 16;
            const unsigned short* sp = src + (size_t)rr * N_ + cc;
            *(short8*)(&T[rr * 264 + cc])     = *(const short8*)(sp);
            *(short8*)(&T[rr * 264 + cc + 8]) = *(const short8*)(sp + 8);
        }
        __syncthreads();
        unsigned short* dst = vfo + (size_t)bs * 1048576;
        const int jb = t >> 5, l0 = (t & 31) * 2;
        #pragma unroll
        for (int u = 0; u < 2; ++u) {
            const int lam = l0 + u, q = lam >> 4, r15 = lam & 15;
            short8 val = *(const short8*)(&T[r15 * 264 + jb * 32 + q * 8]);
            const int j32 = (b & 15) * 8 + jb;
            *(short8*)(dst + ((size_t)(j32 * 16 + ct) * 64 + lam) * 8) = val;
        }
    } else {
        // K: [n][64] -> frag blocks.  Block handles 64 n x 64 kappa.
        const int idx = b - 1024, bs = idx >> 6, n0 = (idx & 63) * 64;
        const unsigned short* src = k_ws + (size_t)bs * (N_ * CQ_) + (size_t)n0 * 64;
        {
            const int rr = t >> 2, cc = (t & 3) * 16;
            const unsigned short* sp = src + (size_t)rr * 64 + cc;
            *(short8*)(&T[rr * 72 + cc])     = *(const short8*)(sp);
            *(short8*)(&T[rr * 72 + cc + 8]) = *(const short8*)(sp + 8);
        }
        __syncthreads();
        unsigned short* dst = kfo + (size_t)bs * 262144;
        const int blk = t >> 5, jtl = blk >> 1, kh = blk & 1, l0 = (t & 31) * 2;
        #pragma unroll
        for (int u = 0; u < 2; ++u) {
            const int lam = l0 + u, q = lam >> 4, r15 = lam & 15;
            short8 val = *(const short8*)(&T[(jtl * 16 + r15) * 72 + kh * 32 + q * 8]);
            *(short8*)(dst + ((size_t)((n0 >> 4) + jtl) * 2 + kh) * 512 + lam * 8) = val;
        }
    }
}

// ---------------------------------------------------------------------------
// MFMA flash attention, v7 = v6 (16 waves, asymmetric roles) with ONE change:
// K/V loads read the fragment-linear Kf/Vf buffers -- each load is a single
// contiguous 1KB wave-burst (lane*16B) instead of 16 scattered 64B lines.
// Everything else (roles, P swizzle, barriers, reductions) is v6-identical
// for clean attribution.
// ---------------------------------------------------------------------------
__global__ __launch_bounds__(1024)
void flash_kernel(const _Float16* __restrict__ qg,        // [bs][n][64] f16
                  const _Float16* __restrict__ kfg,       // frag-linear K
                  const unsigned short* __restrict__ vfg, // frag-linear V
                  const float* __restrict__ in1, const float* __restrict__ in2,
                  const float* __restrict__ gamma_p, float* __restrict__ out)
{
    __shared__ unsigned short Pt[2][64 * 64];   // swizzled, 128 B/row; f32 scratch at end
    __shared__ float lsum[64 * 4];

    const int tid  = threadIdx.x;
    const int lane = tid & 63;
    const int wave = tid >> 6;              // 0..15
    const int quad = lane >> 4;
    const int l15  = lane & 15;
    const int bs   = blockIdx.x & 3;        // one bs per XCD-pair (L2 locality)
    const int q0   = (blockIdx.x >> 2) * 64;
    const int s = bs >> 1, bb = bs & 1;
    // S-role (waves 0-7 only)
    const int jsub  = wave & 3;
    const int ihalf = (wave >> 2) & 1;
    // PV-role (all 16 waves)
    const int wc = wave & 7;                // c-block 32*wc
    const int jh = wave >> 3;               // j-chunk 32*jh of the 64-j tile

    const _Float16* qp = qg + (size_t)bs * N_ * CQ_;
    const _Float16* kB = kfg + (size_t)bs * 262144 + lane * 8;
    const unsigned short* vB = vfg + (size_t)bs * 1048576 + (size_t)lane * 8;

    unsigned char* ptb0 = (unsigned char*)&Pt[0][0];
    unsigned char* ptb1 = (unsigned char*)&Pt[1][0];

    // persistent Q B-frags (S-waves only): i = 32*ihalf + 16*isub + l15
    half8 qf[2][2];
    float lacc[2] = {0.f, 0.f};
    half8 kf[2];            // K(t+1) at top of body t
    short8 vf[2];           // V(t) j-chunk jh at top of body t  [csub]
    f32x4 acc[4][2];        // partial O^T: [is2][csub]
    #pragma unroll
    for (int a = 0; a < 4; ++a)
        #pragma unroll
        for (int bq = 0; bq < 2; ++bq) acc[a][bq] = (f32x4){0.f, 0.f, 0.f, 0.f};

    // ---------------- prologue ----------------
    if (wave < 8) {
        #pragma unroll
        for (int isub = 0; isub < 2; ++isub)
            #pragma unroll
            for (int kh = 0; kh < 2; ++kh)
                qf[isub][kh] = *(const half8*)(
                    qp + (size_t)(q0 + 32 * ihalf + 16 * isub + l15) * CQ_ + quad * 8 + kh * 32);
        kf[0] = *(const half8*)(kB + (size_t)(jsub * 2 + 0) * 512);
        kf[1] = *(const half8*)(kB + (size_t)(jsub * 2 + 1) * 512);
        // S(0) -> Pt[0]
        f32x4 sacc[2];
        sacc[0] = (f32x4){0.f, 0.f, 0.f, 0.f};
        sacc[1] = (f32x4){0.f, 0.f, 0.f, 0.f};
        #pragma unroll
        for (int kh = 0; kh < 2; ++kh)
            #pragma unroll
            for (int isub = 0; isub < 2; ++isub)
                sacc[isub] = __builtin_amdgcn_mfma_f32_16x16x32_f16(
                    kf[kh], qf[isub][kh], sacc[isub], 0, 0, 0);
        #pragma unroll
        for (int isub = 0; isub < 2; ++isub) {
            f32x4 p;
            p.x = __expf(sacc[isub].x - SHIFT);
            p.y = __expf(sacc[isub].y - SHIFT);
            p.z = __expf(sacc[isub].z - SHIFT);
            p.w = __expf(sacc[isub].w - SHIFT);
            lacc[isub] += p.x + p.y + p.z + p.w;
            ushort4 pbv;
            pbv.x = f2bf(p.x); pbv.y = f2bf(p.y); pbv.z = f2bf(p.z); pbv.w = f2bf(p.w);
            int row = 32 * ihalf + 16 * isub + l15;
            int cb  = (32 * jsub + 8 * quad) ^ ((row & 7) << 4);
            *(ushort4*)(ptb0 + row * 128 + cb) = pbv;
        }
        // K(1) for body t=0
        kf[0] = *(const half8*)(kB + (size_t)((4 + jsub) * 2 + 0) * 512);
        kf[1] = *(const half8*)(kB + (size_t)((4 + jsub) * 2 + 1) * 512);
    }
    // V(0) (all waves)
    vf[0] = *(const short8*)(vB + (size_t)(jh * 16 + 2 * wc + 0) * 512);
    vf[1] = *(const short8*)(vB + (size_t)(jh * 16 + 2 * wc + 1) * 512);

    // ---------------- main loop ----------------
    for (int t = 0; t < 64; ++t) {
        unsigned char* ptr = (t & 1) ? ptb1 : ptb0;        // P(t)
        unsigned char* ptw = (t & 1) ? ptb0 : ptb1;        // P(t+1)

        asm volatile("s_waitcnt lgkmcnt(0)" ::: "memory");
        __builtin_amdgcn_sched_barrier(0);
        __builtin_amdgcn_s_barrier();
        __builtin_amdgcn_sched_barrier(0);

        // ---- PV(t): all waves.  O^T_partial += P[i][32jh..+31] x V ----
        short8 ap[4];
        #pragma unroll
        for (int is2 = 0; is2 < 4; ++is2) {
            int row = 16 * is2 + l15;
            int cb  = (jh * 64 + quad * 16) ^ ((row & 7) << 4);
            ap[is2] = *(const short8*)(ptr + row * 128 + cb);
        }
        __builtin_amdgcn_s_setprio(1);
        #pragma unroll
        for (int is2 = 0; is2 < 4; ++is2)
            #pragma unroll
            for (int csub = 0; csub < 2; ++csub)
                acc[is2][csub] = __builtin_amdgcn_mfma_f32_16x16x32_bf16(
                    ap[is2], vf[csub], acc[is2][csub], 0, 0, 0);
        __builtin_amdgcn_s_setprio(0);

        if (t < 63) {
            // ---- S(t+1) + exp + P-write (S-waves) ----
            if (wave < 8) {
                f32x4 sacc[2];
                sacc[0] = (f32x4){0.f, 0.f, 0.f, 0.f};
                sacc[1] = (f32x4){0.f, 0.f, 0.f, 0.f};
                #pragma unroll
                for (int kh = 0; kh < 2; ++kh)
                    #pragma unroll
                    for (int isub = 0; isub < 2; ++isub)
                        sacc[isub] = __builtin_amdgcn_mfma_f32_16x16x32_f16(
                            kf[kh], qf[isub][kh], sacc[isub], 0, 0, 0);
                #pragma unroll
                for (int isub = 0; isub < 2; ++isub) {
                    f32x4 p;
                    p.x = __expf(sacc[isub].x - SHIFT);
                    p.y = __expf(sacc[isub].y - SHIFT);
                    p.z = __expf(sacc[isub].z - SHIFT);
                    p.w = __expf(sacc[isub].w - SHIFT);
                    lacc[isub] += p.x + p.y + p.z + p.w;
                    ushort4 pbv;
                    pbv.x = f2bf(p.x); pbv.y = f2bf(p.y); pbv.z = f2bf(p.z); pbv.w = f2bf(p.w);
                    int row = 32 * ihalf + 16 * isub + l15;
                    int cb  = (32 * jsub + 8 * quad) ^ ((row & 7) << 4);
                    *(ushort4*)(ptw + row * 128 + cb) = pbv;
                }
                // K(t+2) for next body
                int tk = (t + 2) & 63;
                kf[0] = *(const half8*)(kB + (size_t)((tk * 4 + jsub) * 2 + 0) * 512);
                kf[1] = *(const half8*)(kB + (size_t)((tk * 4 + jsub) * 2 + 1) * 512);
            }
            // V(t+1) (all waves; issued after PV consumed vf)
            vf[0] = *(const short8*)(vB + (size_t)((2 * (t + 1) + jh) * 16 + 2 * wc + 0) * 512);
            vf[1] = *(const short8*)(vB + (size_t)((2 * (t + 1) + jh) * 16 + 2 * wc + 1) * 512);
        }
    }

    // ---- l reduction (S-waves): quad-shfl then cross-jsub via LDS ----
    if (wave < 8) {
        #pragma unroll
        for (int isub = 0; isub < 2; ++isub) {
            float t = lacc[isub];
            t += __shfl_xor(t, 16);
            t += __shfl_xor(t, 32);
            if (quad == 0)
                lsum[(32 * ihalf + 16 * isub + l15) * 4 + jsub] = t;
        }
    }
    __syncthreads();

    // ---- jh-reduction: waves 8-15 hand their partial O to partner wave-8 ----
    float* red = (float*)&Pt[0][0];   // 16 KB scratch (Pt no longer needed)
    #pragma unroll
    for (int r = 0; r < 4; ++r) {
        if (wave >= 8) {
            *(f32x4*)(red + (size_t)(wave - 8) * 512 + lane * 8 + 0) = acc[r][0];
            *(f32x4*)(red + (size_t)(wave - 8) * 512 + lane * 8 + 4) = acc[r][1];
        }
        __syncthreads();
        if (wave < 8) {
            f32x4 a0 = *(const f32x4*)(red + (size_t)wave * 512 + lane * 8 + 0);
            f32x4 a1 = *(const f32x4*)(red + (size_t)wave * 512 + lane * 8 + 4);
            acc[r][0] += a0;
            acc[r][1] += a1;
        }
        __syncthreads();
    }

    // ---- epilogue: normalize + gamma + residual (waves 0-7; wc = wave) ----
    if (wave < 8) {
        const float gamma = gamma_p[0];
        const float* inp = (s ? in2 : in1) + (size_t)bb * C_ * N_;
        float* op = out + (size_t)bs * C_ * N_;
        #pragma unroll
        for (int is2 = 0; is2 < 4; ++is2) {
            float inv[4];
            #pragma unroll
            for (int r = 0; r < 4; ++r) {
                f32x4 t = *(const f32x4*)(&lsum[(16 * is2 + quad * 4 + r) * 4]);
                inv[r] = 1.0f / (t.x + t.y + t.z + t.w);
            }
            #pragma unroll
            for (int csub = 0; csub < 2; ++csub) {
                int c = 32 * wc + 16 * csub + l15;
                #pragma unroll
                for (int r = 0; r < 4; ++r) {
                    int i = q0 + 16 * is2 + quad * 4 + r;
                    size_t idx = (size_t)c * N_ + i;
                    op[idx] = gamma * acc[is2][csub][r] * inv[r] + inp[idx];
                }
            }
        }
    }
}

// ---------------------------------------------------------------------------
extern "C" void kernel_launch(void* const* d_in, const int* in_sizes, int n_in,
                              void* d_out, int out_size, void* d_ws, size_t ws_size,
                              hipStream_t stream)
{
    const float* in1 = (const float*)d_in[0];
    const float* in2 = (const float*)d_in[1];
    const float* q1w = (const float*)d_in[2];
    const float* q1b = (const float*)d_in[3];
    const float* k1w = (const float*)d_in[4];
    const float* k1b = (const float*)d_in[5];
    const float* v1w = (const float*)d_in[6];
    const float* v1b = (const float*)d_in[7];
    const float* q2w = (const float*)d_in[8];
    const float* q2b = (const float*)d_in[9];
    const float* k2w = (const float*)d_in[10];
    const float* k2b = (const float*)d_in[11];
    const float* v2w = (const float*)d_in[12];
    const float* v2b = (const float*)d_in[13];
    const float* gamma = (const float*)d_in[22];
    float* out = (float*)d_out;

    // ws (halves): wb 196608 | q 4M/4 | k | v | Kf | Vf
    _Float16* wb   = (_Float16*)d_ws;
    _Float16* q_ws = wb + 196608;
    _Float16* k_ws = q_ws + (size_t)4 * N_ * CQ_;                       // 1048576
    unsigned short* v_ws = (unsigned short*)(k_ws + (size_t)4 * N_ * CQ_);  // 4194304
    unsigned short* kf_ws = v_ws + (size_t)4 * C_ * N_;                 // 1048576
    unsigned short* vf_ws = kf_ws + (size_t)4 * 262144;                 // 4194304

    wconv_kernel<<<dim3(192), 256, 0, stream>>>(q1w, k1w, v1w, q2w, k2w, v2w, wb);
    proj_kernel<<<dim3(64, 4), 512, 0, stream>>>(
        in1, in2, wb, q1b, k1b, v1b, q2b, k2b, v2b, q_ws, k_ws, v_ws);
    repack_kernel<<<dim3(1280), 256, 0, stream>>>(
        v_ws, (const unsigned short*)k_ws, vf_ws, kf_ws);
    flash_kernel<<<dim3(256), 1024, 0, stream>>>(
        q_ws, (const _Float16*)kf_ws, vf_ws, in1, in2, gamma, out);
}

// Round 7
// 178.178 us; speedup vs baseline: 1.2541x; 1.0469x over previous
//
#include <hip/hip_runtime.h>
#include <math.h>

// Problem constants
constexpr int B_  = 2;
constexpr int C_  = 256;
constexpr int CQ_ = 64;
constexpr int N_  = 4096;  // 64*64

typedef __attribute__((ext_vector_type(8))) short     short8;  // 8 bf16
typedef __attribute__((ext_vector_type(8))) _Float16  half8;   // 8 f16
typedef __attribute__((ext_vector_type(4))) float     f32x4;   // MFMA C/D

constexpr float SHIFT = 24.0f;   // static softmax shift (exact: shift-invariance)

static __device__ __forceinline__ unsigned short f2bf(float x) {
    union { float f; unsigned u; } v; v.f = x;
    unsigned r = (v.u + 0x7FFFu + ((v.u >> 16) & 1u)) >> 16;  // RNE
    return (unsigned short)r;
}

// ---------------------------------------------------------------------------
// Weight convert: fp32 -> f16, concat [q1|k1|v1|q2|k2|v2] (96K elems/stream)
// ---------------------------------------------------------------------------
__global__ __launch_bounds__(256)
void wconv_kernel(const float* __restrict__ q1w, const float* __restrict__ k1w,
                  const float* __restrict__ v1w, const float* __restrict__ q2w,
                  const float* __restrict__ k2w, const float* __restrict__ v2w,
                  _Float16* __restrict__ wb)
{
    int i = (blockIdx.x * 256 + threadIdx.x) * 4;   // grid 192 -> 196608 elems
    const float* src;
    int off;
    if      (i < 16384)  { src = q1w; off = 0; }
    else if (i < 32768)  { src = k1w; off = 16384; }
    else if (i < 98304)  { src = v1w; off = 32768; }
    else if (i < 114688) { src = q2w; off = 98304; }
    else if (i < 131072) { src = k2w; off = 114688; }
    else                 { src = v2w; off = 131072; }
    float4 f = *(const float4*)(src + (i - off));
    _Float16 h0 = (_Float16)f.x, h1 = (_Float16)f.y;
    _Float16 h2 = (_Float16)f.z, h3 = (_Float16)f.w;
    ushort4 u;
    u.x = *(unsigned short*)&h0; u.y = *(unsigned short*)&h1;
    u.z = *(unsigned short*)&h2; u.w = *(unsigned short*)&h3;
    *(ushort4*)((unsigned short*)wb + i) = u;
}

// ---------------------------------------------------------------------------
// Fused QKV projection, v8: writes K and V DIRECTLY in the MFMA
// fragment-linear layout consumed by flash (repack kernel deleted):
//   Kf[jt][kh][lane][8] : Kf[...] = K[jt*16 + (lane&15)][kh*32 + (lane>>4)*8 + e]
//   Vf[j32][ct][lane][8]: Vf[...] = V[ct*16 + (lane&15)][j32*32 + (lane>>4)*8 + e]
// Same scalar-store count as the old [n][64]/[c][n] epilogues -- only the
// target addresses differ.  Q output layout unchanged.
// ---------------------------------------------------------------------------
__global__ __launch_bounds__(512)
void proj_kernel(const float* __restrict__ in1, const float* __restrict__ in2,
                 const _Float16* __restrict__ wb,
                 const float* __restrict__ q1b, const float* __restrict__ k1b,
                 const float* __restrict__ v1b, const float* __restrict__ q2b,
                 const float* __restrict__ k2b, const float* __restrict__ v2b,
                 _Float16* __restrict__ q_ws, _Float16* __restrict__ kf_ws,
                 unsigned short* __restrict__ vf_ws)
{
    __shared__ _Float16 Xs[64 * 264];
    const int bs = blockIdx.y, s = bs >> 1, bb = bs & 1;
    const int n0 = blockIdx.x * 64;
    const float* x = (s ? in2 : in1) + (size_t)bb * C_ * N_;
    const int tid = threadIdx.x;
    const int lane = tid & 63, wave = tid >> 6, quad = lane >> 4, l15 = lane & 15;

    #pragma unroll
    for (int rep = 0; rep < 8; ++rep) {
        int idx = rep * 512 + tid;
        int c = idx >> 4, ng = idx & 15;
        float4 f = *(const float4*)(x + (size_t)c * N_ + n0 + ng * 4);
        Xs[(ng * 4 + 0) * 264 + c] = (_Float16)f.x;
        Xs[(ng * 4 + 1) * 264 + c] = (_Float16)f.y;
        Xs[(ng * 4 + 2) * 264 + c] = (_Float16)f.z;
        Xs[(ng * 4 + 3) * 264 + c] = (_Float16)f.w;
    }
    __syncthreads();

    const _Float16* wqs = wb + (size_t)s * 98304;
    const _Float16* wks = wqs + 16384;
    const _Float16* wvs = wks + 16384;

    // ---- Q/K: waves 0-3 -> Q, 4-7 -> K; n-block = wave&3 ----
    {
        const int m = wave >> 2, nb = wave & 3;
        const _Float16* W = m ? wks : wqs;
        const float* bias = m ? (s ? k2b : k1b) : (s ? q2b : q1b);
        half8 af[8];
        #pragma unroll
        for (int kh = 0; kh < 8; ++kh)
            af[kh] = *(const half8*)(&Xs[(16 * nb + l15) * 264 + quad * 8 + kh * 32]);
        f32x4 a4[4];
        #pragma unroll
        for (int o = 0; o < 4; ++o) a4[o] = (f32x4){0.f, 0.f, 0.f, 0.f};
        #pragma unroll
        for (int kh = 0; kh < 8; ++kh)
            #pragma unroll
            for (int o = 0; o < 4; ++o) {
                half8 bf = *(const half8*)(W + (size_t)(16 * o + l15) * C_ + quad * 8 + kh * 32);
                a4[o] = __builtin_amdgcn_mfma_f32_16x16x32_f16(af[kh], bf, a4[o], 0, 0, 0);
            }
        if (m == 0) {
            // Q: [n][64] f16 (flash prologue reads rows; once per block -> cheap)
            _Float16* outp = q_ws + (size_t)bs * N_ * CQ_;
            #pragma unroll
            for (int o = 0; o < 4; ++o) {
                float bv = bias[16 * o + l15];
                #pragma unroll
                for (int r = 0; r < 4; ++r) {
                    int n = n0 + 16 * nb + quad * 4 + r;
                    outp[(size_t)n * CQ_ + 16 * o + l15] = (_Float16)(a4[o][r] + bv);
                }
            }
        } else {
            // K: fragment-linear.  j = n0+16nb+quad*4+r, kappa = 16o+l15.
            // jt = n0/16+nb; kh = o>>1; lane = ((o&1)*2 + (l15>>3))*16 + quad*4+r;
            // e = l15&7.
            unsigned short* kd = (unsigned short*)(kf_ws) + (size_t)bs * 262144;
            const int jt = (n0 >> 4) + nb;
            const int e = l15 & 7;
            #pragma unroll
            for (int o = 0; o < 4; ++o) {
                float bv = bias[16 * o + l15];
                const int kh = o >> 1;
                const int lhi = ((o & 1) * 2 + (l15 >> 3)) * 16;
                #pragma unroll
                for (int r = 0; r < 4; ++r) {
                    _Float16 hv = (_Float16)(a4[o][r] + bv);
                    int lane_f = lhi + quad * 4 + r;
                    kd[(size_t)(jt * 2 + kh) * 512 + lane_f * 8 + e] = *(unsigned short*)&hv;
                }
            }
        }
    }

    // ---- V: wave owns c-block 32*wave .. +31; fragment-linear output ----
    {
        const float* vb = s ? v2b : v1b;
        unsigned short* vd = vf_ws + (size_t)bs * 1048576;
        f32x4 v4[2][4];
        #pragma unroll
        for (int o = 0; o < 2; ++o)
            #pragma unroll
            for (int nt = 0; nt < 4; ++nt) v4[o][nt] = (f32x4){0.f, 0.f, 0.f, 0.f};
        #pragma unroll
        for (int kh = 0; kh < 8; ++kh) {
            half8 bf[4], af[2];
            #pragma unroll
            for (int nt = 0; nt < 4; ++nt)
                bf[nt] = *(const half8*)(&Xs[(16 * nt + l15) * 264 + quad * 8 + kh * 32]);
            #pragma unroll
            for (int o = 0; o < 2; ++o)
                af[o] = *(const half8*)(wvs + (size_t)(32 * wave + 16 * o + l15) * C_ + quad * 8 + kh * 32);
            #pragma unroll
            for (int o = 0; o < 2; ++o)
                #pragma unroll
                for (int nt = 0; nt < 4; ++nt)
                    v4[o][nt] = __builtin_amdgcn_mfma_f32_16x16x32_f16(af[o], bf[nt], v4[o][nt], 0, 0, 0);
        }
        // c = 32*wave+16o+quad*4+r  (ct = 2*wave+o, c&15 = quad*4+r)
        // j = n0+16nt+l15           (j32 = n0/32 + (nt>>1))
        // lane = ((nt&1)*2 + (l15>>3))*16 + quad*4+r ; e = l15&7
        const int e = l15 & 7;
        #pragma unroll
        for (int o = 0; o < 2; ++o) {
            const int ct = 2 * wave + o;
            #pragma unroll
            for (int r = 0; r < 4; ++r) {
                int c = 32 * wave + 16 * o + quad * 4 + r;
                float bv = vb[c];
                #pragma unroll
                for (int nt = 0; nt < 4; ++nt) {
                    const int j32 = (n0 >> 5) + (nt >> 1);
                    const int lane_f = ((nt & 1) * 2 + (l15 >> 3)) * 16 + quad * 4 + r;
                    vd[(size_t)(j32 * 16 + ct) * 512 + lane_f * 8 + e] =
                        f2bf(v4[o][nt][r] + bv);
                }
            }
        }
    }
}

// ---------------------------------------------------------------------------
// MFMA flash attention, v8 = v7 (16 waves, frag-linear K/V) with ONE change:
// the P-pack uses v_cvt_pk_bf16_f32 (2 insts for 4 values) instead of the
// 6-op manual-RNE bit-twiddle (same RNE result bits).  VALUBusy was 31.5%
// with ~48 pack ops per S-wave per iter; this removes ~44 of them.
// ---------------------------------------------------------------------------
__global__ __launch_bounds__(1024)
void flash_kernel(const _Float16* __restrict__ qg,        // [bs][n][64] f16
                  const _Float16* __restrict__ kfg,       // frag-linear K
                  const unsigned short* __restrict__ vfg, // frag-linear V
                  const float* __restrict__ in1, const float* __restrict__ in2,
                  const float* __restrict__ gamma_p, float* __restrict__ out)
{
    __shared__ unsigned short Pt[2][64 * 64];   // swizzled, 128 B/row; f32 scratch at end
    __shared__ float lsum[64 * 4];

    const int tid  = threadIdx.x;
    const int lane = tid & 63;
    const int wave = tid >> 6;              // 0..15
    const int quad = lane >> 4;
    const int l15  = lane & 15;
    const int bs   = blockIdx.x & 3;        // one bs per XCD-pair (L2 locality)
    const int q0   = (blockIdx.x >> 2) * 64;
    const int s = bs >> 1, bb = bs & 1;
    // S-role (waves 0-7 only)
    const int jsub  = wave & 3;
    const int ihalf = (wave >> 2) & 1;
    // PV-role (all 16 waves)
    const int wc = wave & 7;                // c-block 32*wc
    const int jh = wave >> 3;               // j-chunk 32*jh of the 64-j tile

    const _Float16* qp = qg + (size_t)bs * N_ * CQ_;
    const _Float16* kB = kfg + (size_t)bs * 262144 + lane * 8;
    const unsigned short* vB = vfg + (size_t)bs * 1048576 + (size_t)lane * 8;

    unsigned char* ptb0 = (unsigned char*)&Pt[0][0];
    unsigned char* ptb1 = (unsigned char*)&Pt[1][0];

    // persistent Q B-frags (S-waves only): i = 32*ihalf + 16*isub + l15
    half8 qf[2][2];
    float lacc[2] = {0.f, 0.f};
    half8 kf[2];            // K(t+1) at top of body t
    short8 vf[2];           // V(t) j-chunk jh at top of body t  [csub]
    f32x4 acc[4][2];        // partial O^T: [is2][csub]
    #pragma unroll
    for (int a = 0; a < 4; ++a)
        #pragma unroll
        for (int bq = 0; bq < 2; ++bq) acc[a][bq] = (f32x4){0.f, 0.f, 0.f, 0.f};

    // ---------------- prologue ----------------
    if (wave < 8) {
        #pragma unroll
        for (int isub = 0; isub < 2; ++isub)
            #pragma unroll
            for (int kh = 0; kh < 2; ++kh)
                qf[isub][kh] = *(const half8*)(
                    qp + (size_t)(q0 + 32 * ihalf + 16 * isub + l15) * CQ_ + quad * 8 + kh * 32);
        kf[0] = *(const half8*)(kB + (size_t)(jsub * 2 + 0) * 512);
        kf[1] = *(const half8*)(kB + (size_t)(jsub * 2 + 1) * 512);
        // S(0) -> Pt[0]
        f32x4 sacc[2];
        sacc[0] = (f32x4){0.f, 0.f, 0.f, 0.f};
        sacc[1] = (f32x4){0.f, 0.f, 0.f, 0.f};
        #pragma unroll
        for (int kh = 0; kh < 2; ++kh)
            #pragma unroll
            for (int isub = 0; isub < 2; ++isub)
                sacc[isub] = __builtin_amdgcn_mfma_f32_16x16x32_f16(
                    kf[kh], qf[isub][kh], sacc[isub], 0, 0, 0);
        #pragma unroll
        for (int isub = 0; isub < 2; ++isub) {
            f32x4 p;
            p.x = __expf(sacc[isub].x - SHIFT);
            p.y = __expf(sacc[isub].y - SHIFT);
            p.z = __expf(sacc[isub].z - SHIFT);
            p.w = __expf(sacc[isub].w - SHIFT);
            lacc[isub] += p.x + p.y + p.z + p.w;
            unsigned pk0, pk1;
            asm("v_cvt_pk_bf16_f32 %0, %1, %2" : "=v"(pk0) : "v"(p.x), "v"(p.y));
            asm("v_cvt_pk_bf16_f32 %0, %1, %2" : "=v"(pk1) : "v"(p.z), "v"(p.w));
            int row = 32 * ihalf + 16 * isub + l15;
            int cb  = (32 * jsub + 8 * quad) ^ ((row & 7) << 4);
            uint2 pbv; pbv.x = pk0; pbv.y = pk1;
            *(uint2*)(ptb0 + row * 128 + cb) = pbv;
        }
        // K(1) for body t=0
        kf[0] = *(const half8*)(kB + (size_t)((4 + jsub) * 2 + 0) * 512);
        kf[1] = *(const half8*)(kB + (size_t)((4 + jsub) * 2 + 1) * 512);
    }
    // V(0) (all waves)
    vf[0] = *(const short8*)(vB + (size_t)(jh * 16 + 2 * wc + 0) * 512);
    vf[1] = *(const short8*)(vB + (size_t)(jh * 16 + 2 * wc + 1) * 512);

    // ---------------- main loop ----------------
    for (int t = 0; t < 64; ++t) {
        unsigned char* ptr = (t & 1) ? ptb1 : ptb0;        // P(t)
        unsigned char* ptw = (t & 1) ? ptb0 : ptb1;        // P(t+1)

        asm volatile("s_waitcnt lgkmcnt(0)" ::: "memory");
        __builtin_amdgcn_sched_barrier(0);
        __builtin_amdgcn_s_barrier();
        __builtin_amdgcn_sched_barrier(0);

        // ---- PV(t): all waves.  O^T_partial += P[i][32jh..+31] x V ----
        short8 ap[4];
        #pragma unroll
        for (int is2 = 0; is2 < 4; ++is2) {
            int row = 16 * is2 + l15;
            int cb  = (jh * 64 + quad * 16) ^ ((row & 7) << 4);
            ap[is2] = *(const short8*)(ptr + row * 128 + cb);
        }
        __builtin_amdgcn_s_setprio(1);
        #pragma unroll
        for (int is2 = 0; is2 < 4; ++is2)
            #pragma unroll
            for (int csub = 0; csub < 2; ++csub)
                acc[is2][csub] = __builtin_amdgcn_mfma_f32_16x16x32_bf16(
                    ap[is2], vf[csub], acc[is2][csub], 0, 0, 0);
        __builtin_amdgcn_s_setprio(0);

        if (t < 63) {
            // ---- S(t+1) + exp + P-write (S-waves) ----
            if (wave < 8) {
                f32x4 sacc[2];
                sacc[0] = (f32x4){0.f, 0.f, 0.f, 0.f};
                sacc[1] = (f32x4){0.f, 0.f, 0.f, 0.f};
                #pragma unroll
                for (int kh = 0; kh < 2; ++kh)
                    #pragma unroll
                    for (int isub = 0; isub < 2; ++isub)
                        sacc[isub] = __builtin_amdgcn_mfma_f32_16x16x32_f16(
                            kf[kh], qf[isub][kh], sacc[isub], 0, 0, 0);
                #pragma unroll
                for (int isub = 0; isub < 2; ++isub) {
                    f32x4 p;
                    p.x = __expf(sacc[isub].x - SHIFT);
                    p.y = __expf(sacc[isub].y - SHIFT);
                    p.z = __expf(sacc[isub].z - SHIFT);
                    p.w = __expf(sacc[isub].w - SHIFT);
                    lacc[isub] += p.x + p.y + p.z + p.w;
                    unsigned pk0, pk1;
                    asm("v_cvt_pk_bf16_f32 %0, %1, %2" : "=v"(pk0) : "v"(p.x), "v"(p.y));
                    asm("v_cvt_pk_bf16_f32 %0, %1, %2" : "=v"(pk1) : "v"(p.z), "v"(p.w));
                    int row = 32 * ihalf + 16 * isub + l15;
                    int cb  = (32 * jsub + 8 * quad) ^ ((row & 7) << 4);
                    uint2 pbv; pbv.x = pk0; pbv.y = pk1;
                    *(uint2*)(ptw + row * 128 + cb) = pbv;
                }
                // K(t+2) for next body
                int tk = (t + 2) & 63;
                kf[0] = *(const half8*)(kB + (size_t)((tk * 4 + jsub) * 2 + 0) * 512);
                kf[1] = *(const half8*)(kB + (size_t)((tk * 4 + jsub) * 2 + 1) * 512);
            }
            // V(t+1) (all waves; issued after PV consumed vf)
            vf[0] = *(const short8*)(vB + (size_t)((2 * (t + 1) + jh) * 16 + 2 * wc + 0) * 512);
            vf[1] = *(const short8*)(vB + (size_t)((2 * (t + 1) + jh) * 16 + 2 * wc + 1) * 512);
        }
    }

    // ---- l reduction (S-waves): quad-shfl then cross-jsub via LDS ----
    if (wave < 8) {
        #pragma unroll
        for (int isub = 0; isub < 2; ++isub) {
            float t = lacc[isub];
            t += __shfl_xor(t, 16);
            t += __shfl_xor(t, 32);
            if (quad == 0)
                lsum[(32 * ihalf + 16 * isub + l15) * 4 + jsub] = t;
        }
    }
    __syncthreads();

    // ---- jh-reduction: waves 8-15 hand their partial O to partner wave-8 ----
    float* red = (float*)&Pt[0][0];   // 16 KB scratch (Pt no longer needed)
    #pragma unroll
    for (int r = 0; r < 4; ++r) {
        if (wave >= 8) {
            *(f32x4*)(red + (size_t)(wave - 8) * 512 + lane * 8 + 0) = acc[r][0];
            *(f32x4*)(red + (size_t)(wave - 8) * 512 + lane * 8 + 4) = acc[r][1];
        }
        __syncthreads();
        if (wave < 8) {
            f32x4 a0 = *(const f32x4*)(red + (size_t)wave * 512 + lane * 8 + 0);
            f32x4 a1 = *(const f32x4*)(red + (size_t)wave * 512 + lane * 8 + 4);
            acc[r][0] += a0;
            acc[r][1] += a1;
        }
        __syncthreads();
    }

    // ---- epilogue: normalize + gamma + residual (waves 0-7; wc = wave) ----
    if (wave < 8) {
        const float gamma = gamma_p[0];
        const float* inp = (s ? in2 : in1) + (size_t)bb * C_ * N_;
        float* op = out + (size_t)bs * C_ * N_;
        #pragma unroll
        for (int is2 = 0; is2 < 4; ++is2) {
            float inv[4];
            #pragma unroll
            for (int r = 0; r < 4; ++r) {
                f32x4 t = *(const f32x4*)(&lsum[(16 * is2 + quad * 4 + r) * 4]);
                inv[r] = 1.0f / (t.x + t.y + t.z + t.w);
            }
            #pragma unroll
            for (int csub = 0; csub < 2; ++csub) {
                int c = 32 * wc + 16 * csub + l15;
                #pragma unroll
                for (int r = 0; r < 4; ++r) {
                    int i = q0 + 16 * is2 + quad * 4 + r;
                    size_t idx = (size_t)c * N_ + i;
                    op[idx] = gamma * acc[is2][csub][r] * inv[r] + inp[idx];
                }
            }
        }
    }
}

// ---------------------------------------------------------------------------
extern "C" void kernel_launch(void* const* d_in, const int* in_sizes, int n_in,
                              void* d_out, int out_size, void* d_ws, size_t ws_size,
                              hipStream_t stream)
{
    const float* in1 = (const float*)d_in[0];
    const float* in2 = (const float*)d_in[1];
    const float* q1w = (const float*)d_in[2];
    const float* q1b = (const float*)d_in[3];
    const float* k1w = (const float*)d_in[4];
    const float* k1b = (const float*)d_in[5];
    const float* v1w = (const float*)d_in[6];
    const float* v1b = (const float*)d_in[7];
    const float* q2w = (const float*)d_in[8];
    const float* q2b = (const float*)d_in[9];
    const float* k2w = (const float*)d_in[10];
    const float* k2b = (const float*)d_in[11];
    const float* v2w = (const float*)d_in[12];
    const float* v2b = (const float*)d_in[13];
    const float* gamma = (const float*)d_in[22];
    float* out = (float*)d_out;

    // ws: wb f16 196608 | q[4][4096][64] f16 | Kf 4x262144 f16 | Vf 4x1048576 bf16
    _Float16* wb   = (_Float16*)d_ws;
    _Float16* q_ws = wb + 196608;
    _Float16* kf_ws = q_ws + (size_t)4 * N_ * CQ_;
    unsigned short* vf_ws = (unsigned short*)(kf_ws + (size_t)4 * 262144);

    wconv_kernel<<<dim3(192), 256, 0, stream>>>(q1w, k1w, v1w, q2w, k2w, v2w, wb);
    proj_kernel<<<dim3(64, 4), 512, 0, stream>>>(
        in1, in2, wb, q1b, k1b, v1b, q2b, k2b, v2b, q_ws, kf_ws, vf_ws);
    flash_kernel<<<dim3(256), 1024, 0, stream>>>(
        q_ws, kf_ws, vf_ws, in1, in2, gamma, out);
}